// Round 2
// baseline (608.111 us; speedup 1.0000x reference)
//
#include <hip/hip_runtime.h>
#include <stdint.h>

#define CIN 64
#define COUT 128
#define BLOCK 256
#define ROWS_PER_WAVE 64    // 4 MFMA tiles of 16 rows per wave

typedef __attribute__((ext_vector_type(8))) __bf16 bf16x8;
typedef __attribute__((ext_vector_type(4))) float f32x4;

// ---------------------------------------------------------------------------
// Phase 1: inverse rulebook. Each (output voxel, tap) has at most one input
// row, so plain stores suffice (no atomics). Vectorized x4.
// ---------------------------------------------------------------------------
__global__ void scatter_inv_kernel(const int* __restrict__ kz,
                                   const int* __restrict__ oid,
                                   int* __restrict__ inv0,
                                   int* __restrict__ inv1,
                                   int n) {
    int i = (blockIdx.x * blockDim.x + threadIdx.x) * 4;
    if (i + 3 < n) {
        int4 k = *(const int4*)(kz + i);
        int4 o = *(const int4*)(oid + i);
        (k.x ? inv1 : inv0)[o.x] = i + 1;
        (k.y ? inv1 : inv0)[o.y] = i + 2;
        (k.z ? inv1 : inv0)[o.z] = i + 3;
        (k.w ? inv1 : inv0)[o.w] = i + 4;
    } else {
        for (; i < n; ++i) {
            if (kz[i]) inv1[oid[i]] = i + 1;
            else       inv0[oid[i]] = i + 1;
        }
    }
}

// ---------------------------------------------------------------------------
// Phase 2: gather-GEMM + BN + ReLU.
//  - A fragments gathered DIRECTLY global->registers (no LDS, no barriers in
//    the loop): lane loads row inv[tap][tb + (lane&15)], bytes quad*32 (+16)
//    (+128 per k-half). One instr = 16 rows x 128B contiguous.
//  - B (Wcat^T, bf16) in LDS, XOR-swizzled: chunk pc = kc ^ (n&7) makes every
//    ds_read_b128 hit each 4-bank group with exactly 8 lanes (conflict-free).
//  - Missing taps read a zero page (branchless address select).
//  - LDS = 33.8KB -> 4 blocks/CU; no __syncthreads after W staging.
// ---------------------------------------------------------------------------
__launch_bounds__(BLOCK, 4)
__global__ void spconv_bn_relu_kernel(const float* __restrict__ feat,
                                      const float* __restrict__ W,
                                      const float* __restrict__ gamma,
                                      const float* __restrict__ beta,
                                      const float* __restrict__ rmean,
                                      const float* __restrict__ rvar,
                                      const int* __restrict__ inv0,
                                      const int* __restrict__ inv1,
                                      const float* __restrict__ zp,
                                      const int* __restrict__ n_out_p,
                                      float* __restrict__ out,
                                      int N) {
    __shared__ unsigned short wT[COUT * 128];   // 32 KB, swizzled [n][k] bf16
    __shared__ float s_scale[COUT];
    __shared__ float s_bias[COUT];

    const int tid = threadIdx.x;

    // ---- stage Wcat^T into LDS (once per block), bf16, XOR-swizzled ----
    // W global layout: flat = k*128 + n, k = tap*64 + cin
    const float4* W4 = (const float4*)W;
    #pragma unroll
    for (int u = 0; u < 16; ++u) {
        int f4 = u * BLOCK + tid;      // 0..4095
        int n4 = f4 & 31;
        int k  = f4 >> 5;              // 0..127
        float4 v = W4[f4];
        int kc = k >> 3, jj = k & 7;
        float vals[4] = {v.x, v.y, v.z, v.w};
        #pragma unroll
        for (int e = 0; e < 4; ++e) {
            int n = n4 * 4 + e;
            __bf16 h = (__bf16)vals[e];
            wT[n * 128 + ((kc ^ (n & 7)) << 3) + jj] = __builtin_bit_cast(unsigned short, h);
        }
    }
    if (tid < COUT) {
        float s = gamma[tid] * rsqrtf(rvar[tid] + 1e-5f);
        s_scale[tid] = s;
        s_bias[tid]  = fmaf(-rmean[tid], s, beta[tid]);
    }
    __syncthreads();   // the ONLY barrier

    const int nout = *n_out_p;
    const int lane = tid & 63;
    const int m = lane & 15;           // MFMA row within tile / B col
    const int q = lane >> 4;           // quad
    const int wave_gid = blockIdx.x * 4 + (tid >> 6);
    const int wbase = wave_gid * ROWS_PER_WAVE;

    // ---- prologue: all 8 inv indices for this wave's 4 tiles ----
    int idx0[4], idx1[4];
    #pragma unroll
    for (int j = 0; j < 4; ++j) {
        int o = wbase + j * 16 + m;
        idx0[j] = (o < N) ? inv0[o] : 0;
        idx1[j] = (o < N) ? inv1[o] : 0;
    }

    float4 raw[8];
    bf16x8 af[4];

    // issue the 8 gather loads for tile j (A-fragment layout, 2x16B per s)
    auto issue = [&](int j) {
        const float* p0 = idx0[j] ? feat + (size_t)(idx0[j] - 1) * 64 : zp;
        const float* p1 = idx1[j] ? feat + (size_t)(idx1[j] - 1) * 64 : zp;
        #pragma unroll
        for (int s = 0; s < 4; ++s) {
            const float* p = (s < 2 ? p0 : p1) + (s & 1) * 32 + q * 8;
            raw[s * 2 + 0] = *(const float4*)(p);
            raw[s * 2 + 1] = *(const float4*)(p + 4);
        }
    };

    auto convert = [&]() {
        #pragma unroll
        for (int s = 0; s < 4; ++s) {
            float4 a = raw[s * 2], b2 = raw[s * 2 + 1];
            bf16x8 f;
            f[0] = (__bf16)a.x;  f[1] = (__bf16)a.y;
            f[2] = (__bf16)a.z;  f[3] = (__bf16)a.w;
            f[4] = (__bf16)b2.x; f[5] = (__bf16)b2.y;
            f[6] = (__bf16)b2.z; f[7] = (__bf16)b2.w;
            af[s] = f;
        }
    };

    issue(0);
    #pragma unroll
    for (int j = 0; j < 4; ++j) {
        convert();                    // waits raw(j)
        if (j < 3) issue(j + 1);      // next tile's gathers fly during compute
        const int tb = wbase + j * 16;
        #pragma unroll
        for (int c = 0; c < 8; ++c) {
            const int n = c * 16 + m;
            f32x4 acc = {0.f, 0.f, 0.f, 0.f};
            #pragma unroll
            for (int s = 0; s < 4; ++s) {
                int kc = s * 4 + q;
                bf16x8 bf = *(const bf16x8*)&wT[n * 128 + ((kc ^ (n & 7)) << 3)];
                acc = __builtin_amdgcn_mfma_f32_16x16x32_bf16(af[s], bf, acc, 0, 0, 0);
            }
            const float sc = s_scale[n];
            const float bi = s_bias[n];
            const int rb = tb + q * 4;
            #pragma unroll
            for (int r = 0; r < 4; ++r) {
                int o = rb + r;
                if (o < N) {
                    float v = (o < nout) ? fmaxf(fmaf(acc[r], sc, bi), 0.f) : 0.f;
                    out[(size_t)o * COUT + n] = v;
                }
            }
        }
    }
}

extern "C" void kernel_launch(void* const* d_in, const int* in_sizes, int n_in,
                              void* d_out, int out_size, void* d_ws, size_t ws_size,
                              hipStream_t stream) {
    const float* feat  = (const float*)d_in[0];
    const float* W     = (const float*)d_in[1];
    const float* gamma = (const float*)d_in[2];
    const float* beta  = (const float*)d_in[3];
    const float* rmean = (const float*)d_in[4];
    const float* rvar  = (const float*)d_in[5];
    const int*   kz    = (const int*)d_in[6];
    const int*   oid   = (const int*)d_in[7];
    const int*   noutp = (const int*)d_in[8];
    float* out = (float*)d_out;

    const int N = in_sizes[6];   // 600000

    int* inv0 = (int*)d_ws;
    int* inv1 = inv0 + N;
    float* zp = (float*)(inv1 + N);   // 64-float zero page for missing taps

    // clear inv maps + zero page (ws is re-poisoned before every call)
    hipMemsetAsync(d_ws, 0, (size_t)2 * N * sizeof(int) + 64 * sizeof(float), stream);

    int sb = (N + 1023) / 1024;
    scatter_inv_kernel<<<sb, 256, 0, stream>>>(kz, oid, inv0, inv1, N);

    int grid = (N + BLOCK - 1) / BLOCK;   // 1 row per thread -> 64 rows per wave
    spconv_bn_relu_kernel<<<grid, BLOCK, 0, stream>>>(
        feat, W, gamma, beta, rmean, rvar, inv0, inv1, zp, noutp, out, N);
}